// Round 11
// baseline (112.486 us; speedup 1.0000x reference)
//
#include <hip/hip_runtime.h>
#include <hip/hip_bf16.h>

typedef __attribute__((ext_vector_type(8))) short short8;   // 8 bf16 (MFMA A/B frag)
typedef __attribute__((ext_vector_type(4))) float floatx4;  // MFMA C/D frag
typedef unsigned int u32;

#define D_DIM 256
#define TCOLS 32      // B-tile width -> dbuf LDS = 2*32*256*2 = 32768 B
#define TILES 8       // tiles per block -> 256 cols/block -> grid 32x32 = 1024 blocks = 4/CU
#define IDX_BITS 0x1FFFu      // 13-bit index payload (N=M=8192)
#define VAL_MASK 0xFFFFE000u  // truncated value bits (sim+2 positive -> raw bits monotone)

// ---------- helpers ----------

__device__ inline unsigned short f2bf_rne(float f) {
  u32 u = __float_as_uint(f);
  u32 r = (u + 0x7FFFu + ((u >> 16) & 1u)) >> 16;
  return (unsigned short)r;
}

__device__ inline u32 umax(u32 a, u32 b) { return a > b ? a : b; }

__device__ inline void async_ld16(const void* g, void* l) {
  __builtin_amdgcn_global_load_lds((const __attribute__((address_space(1))) void*)g,
                                   (__attribute__((address_space(3))) void*)l, 16, 0, 0);
}

// ---------- kernels ----------

// B only: [256][8192] f32 -> [8192][256] bf16. Coalesced 256B reads/wave,
// 16B short8 stores. Folds best-array init. (A is cast inline in the GEMM.)
__global__ __launch_bounds__(256) void transpose_cast(const float* __restrict__ src,
                                                      unsigned short* __restrict__ dst, int C,
                                                      u32* __restrict__ best, int init_n) {
  const int tid = threadIdx.x;
  const int d = blockIdx.x * 64 + (tid & 63);     // descriptor index
  const int chunk = blockIdx.y * 4 + (tid >> 6);  // 8-feature chunk, 0..31
  const int f0 = chunk * 8;
  float v[8];
#pragma unroll
  for (int u = 0; u < 8; ++u) v[u] = src[(size_t)(f0 + u) * C + d];
  short8 o;
#pragma unroll
  for (int u = 0; u < 8; ++u) o[u] = (short)f2bf_rne(v[u]);
  *(short8*)(dst + (size_t)d * D_DIM + f0) = o;
  if (blockIdx.y == 0) {
    int i = blockIdx.x * 256 + tid;  // 128 x 256 = 32768 >= 16384
    if (i < init_n) best[i] = 0u;
  }
}

// Full-K-in-registers GEMM + fused argmax. 256 threads, 4 waves x 64 rows.
// LDS = 32 KB total; R10 measured 2 blocks/CU co-resident at this size
// (vs 1 block at >=64 KB). TILES=8 doubles the grid to 1024 blocks = 4/CU
// target: more co-resident waves/SIMD to interleave MFMA, ds_read chains,
// epilogue VALU, and per-tile barrier drains across INDEPENDENT blocks.
// acc init = +2.0: outputs sim+2 in [1,3), positive -> raw IEEE bits
// monotone under unsigned compare -> no fmap in the epilogue.
__global__ __launch_bounds__(256, 1) void gemm_reduce(const float* __restrict__ A,
                                                      const unsigned short* __restrict__ Bt,
                                                      u32* __restrict__ best01,
                                                      u32* __restrict__ best10,
                                                      int N) {
  __shared__ alignas(16) unsigned short sB[2][TCOLS * D_DIM];  // 2 x 16 KB = 32768 B

  const int tid  = threadIdx.x;
  const int wave = tid >> 6;
  const int lane = tid & 63;
  const int quad = lane >> 4;
  const int l15  = lane & 15;
  const int n0   = blockIdx.x * 256;
  const int mg0  = blockIdx.y * (TILES * TCOLS);
  const int rbase = n0 + wave * 64;   // 64 rows per wave

  // stage B tile 0 into buf 0 (LDS dest = uniform base + tid*16 — required)
  {
    const unsigned short* src = Bt + (size_t)mg0 * D_DIM;
#pragma unroll
    for (int c = 0; c < 4; ++c) {     // 1024 slots / 256 threads
      int slot = c * 256 + tid;
      int r = slot >> 5, cc = slot & 31;
      int ccg = (cc & 24) | ((cc ^ r) & 7);  // XOR-swizzle spreads frag-read banks
      async_ld16(src + (size_t)r * D_DIM + ccg * 8, (unsigned short*)sB[0] + slot * 8);
    }
  }

  // A fragments: wave's 64 rows x full K=256 from f32 [256][N], cast to bf16.
  // Per (t,kc,u): 16 lanes (l15) read 16 consecutive f32 = 64B segments.
  short8 af[4][8];
#pragma unroll
  for (int t = 0; t < 4; ++t)
#pragma unroll
    for (int kc = 0; kc < 8; ++kc) {
      const int row = rbase + t * 16 + l15;
      const int kb = kc * 32 + quad * 8;
      short8 o;
#pragma unroll
      for (int u = 0; u < 8; ++u)
        o[u] = (short)f2bf_rne(A[(size_t)(kb + u) * N + row]);
      af[t][kc] = o;
    }

  u32 rbk[16];  // running row-argmax keys (16 rows per lane)
#pragma unroll
  for (int s = 0; s < 16; ++s) rbk[s] = 0u;

  __syncthreads();  // drains vmcnt: B0 staged

  for (int mt = 0; mt < TILES; ++mt) {
    const int m0 = mg0 + mt * TCOLS;
    if (mt + 1 < TILES) {  // prefetch next B tile — latency hides under MFMA
      const unsigned short* src = Bt + (size_t)(m0 + TCOLS) * D_DIM;
      unsigned short* dstb = (unsigned short*)sB[(mt + 1) & 1];
#pragma unroll
      for (int c = 0; c < 4; ++c) {
        int slot = c * 256 + tid;
        int r = slot >> 5, cc = slot & 31;
        int ccg = (cc & 24) | ((cc ^ r) & 7);
        async_ld16(src + (size_t)r * D_DIM + ccg * 8, dstb + slot * 8);
      }
    }

    floatx4 acc[4][2];
#pragma unroll
    for (int i = 0; i < 4; ++i)
#pragma unroll
      for (int j = 0; j < 2; ++j)
        acc[i][j] = (floatx4){2.0f, 2.0f, 2.0f, 2.0f};  // bias: outputs = sim+2 > 0

    const unsigned short* sb = (const unsigned short*)sB[mt & 1];
#pragma unroll
    for (int kc = 0; kc < 8; ++kc) {
      short8 bfr[2];
#pragma unroll
      for (int j = 0; j < 2; ++j) {
        int c2 = j * 16 + l15;
        int ch = kc * 4 + quad;
        int chg = (ch & 24) | ((ch ^ c2) & 7);  // un-swizzle
        bfr[j] = *(const short8*)(sb + c2 * D_DIM + chg * 8);
      }
#pragma unroll
      for (int i = 0; i < 4; ++i)
#pragma unroll
        for (int j = 0; j < 2; ++j)
          acc[i][j] = __builtin_amdgcn_mfma_f32_16x16x32_bf16(af[i][kc], bfr[j], acc[i][j], 0, 0, 0);
    }

    // ---- epilogue. C/D map: col = j*16 + l15, row = i*16 + quad*4 + r
    u32 cb[2] = {0u, 0u};
    u32 colpay[2];
#pragma unroll
    for (int j = 0; j < 2; ++j) colpay[j] = (~(u32)(m0 + j * 16 + l15)) & IDX_BITS;
#pragma unroll
    for (int i = 0; i < 4; ++i)
#pragma unroll
      for (int r = 0; r < 4; ++r) {
        u32 rowpay = (~(u32)(rbase + i * 16 + quad * 4 + r)) & IDX_BITS;
        u32 rb = rbk[i * 4 + r];
#pragma unroll
        for (int j = 0; j < 2; ++j) {
          u32 u = __float_as_uint(acc[i][j][r]) & VAL_MASK;  // positive -> monotone
          rb = umax(rb, u | colpay[j]);
          cb[j] = umax(cb[j], u | rowpay);
        }
        rbk[i * 4 + r] = rb;
      }
    // col-argmax: butterfly over the 4 quads, then DIRECT global atomics
#pragma unroll
    for (int j = 0; j < 2; ++j) {
      u32 b = cb[j];
      b = umax(b, (u32)__shfl_xor((int)b, 16, 64));
      b = umax(b, (u32)__shfl_xor((int)b, 32, 64));
      if (quad == 0) atomicMax(&best10[m0 + j * 16 + l15], b);
    }
    __syncthreads();  // all ds_reads of sb done; vmcnt drained -> next B ready
  }

  // ---- final row reduction: butterfly over l15, one atomic per row
#pragma unroll
  for (int i = 0; i < 4; ++i)
#pragma unroll
    for (int r = 0; r < 4; ++r) {
      u32 b = rbk[i * 4 + r];
      b = umax(b, (u32)__shfl_xor((int)b, 1, 64));
      b = umax(b, (u32)__shfl_xor((int)b, 2, 64));
      b = umax(b, (u32)__shfl_xor((int)b, 4, 64));
      b = umax(b, (u32)__shfl_xor((int)b, 8, 64));
      if (l15 == 0) atomicMax(&best01[rbase + i * 16 + quad * 4 + r], b);
    }
}

__global__ void finalize(const u32* __restrict__ best01, const u32* __restrict__ best10,
                         float* __restrict__ out, int N) {
  int n = blockIdx.x * blockDim.x + threadIdx.x;
  if (n >= N) return;
  u32 k = best01[n];
  int idx01 = (int)((~k) & IDX_BITS);
  float sim = __uint_as_float(k & VAL_MASK) - 2.0f;  // undo +2 bias
  int idx10 = (int)((~best10[idx01]) & IDX_BITS);
  float dist = 2.0f - 2.0f * sim;             // squared L2 for unit vectors
  bool ok = (idx10 == n) && (dist <= 0.64f);  // mutual NN + thresh^2
  out[n]     = ok ? (float)idx01 : -1.0f;
  out[N + n] = ok ? 1.5f - sim : 0.0f;        // (dist+1)/2
}

// ---------- launcher ----------

extern "C" void kernel_launch(void* const* d_in, const int* in_sizes, int n_in,
                              void* d_out, int out_size, void* d_ws, size_t ws_size,
                              hipStream_t stream) {
  (void)n_in; (void)out_size; (void)ws_size;
  const float* d0 = (const float*)d_in[0];  // [256][N]
  const float* d1 = (const float*)d_in[1];  // [256][M]
  const int N = in_sizes[0] / D_DIM;        // 8192
  const int M = in_sizes[1] / D_DIM;        // 8192

  u32* best01 = (u32*)d_ws;                            // N u32
  u32* best10 = best01 + N;                            // M u32
  unsigned short* Bt = (unsigned short*)(best10 + M);  // [M][256] bf16
  float* out = (float*)d_out;

  hipLaunchKernelGGL(transpose_cast, dim3(M / 64, 8), dim3(256), 0, stream,
                     d1, Bt, M, best01, N + M);
  hipLaunchKernelGGL(gemm_reduce, dim3(N / 256, M / (TILES * TCOLS)), dim3(256), 0, stream,
                     d0, Bt, best01, best10, N);
  hipLaunchKernelGGL(finalize, dim3(N / 256), dim3(256), 0, stream, best01, best10, out, N);
}